// Round 5
// baseline (264.875 us; speedup 1.0000x reference)
//
#include <hip/hip_runtime.h>
#include <cstdint>
#include <cstddef>

#define M_DIM 4096   // B*S
#define N_DIM 4096   // DOUT
#define K_DIM 4096   // DIN
#define BM 128
#define BN 128
#define BKB 128      // K-tile bytes (=128 i8 elems)

typedef __attribute__((ext_vector_type(4))) int i32x4;
typedef __attribute__((ext_vector_type(16))) int i32x16;

// async global->LDS, 16B per lane. LDS dest is wave-uniform base + lane*16.
__device__ __forceinline__ void async_copy16(const void* g, void* l) {
  __builtin_amdgcn_global_load_lds(
      (const __attribute__((address_space(1))) void*)g,
      (__attribute__((address_space(3))) void*)l,
      16, 0, 0);
}

// ---------------------------------------------------------------------------
// Fused prep kernel. Blocks [0,4096): per-row int8 quant of x -> xi, plus
// folded epilogue coefficients am[m] = scale*rowmax/127,
// bm[m] = am*(128-zp)*sum_k(xi). Blocks [4096,8192): q int32 [K][N] ->
// qsT int8 [N][K] with value (q-128), via 64x64 LDS transpose.
// ---------------------------------------------------------------------------
__global__ __launch_bounds__(256) void prep_kernel(
    const float* __restrict__ x, const int* __restrict__ q,
    const float* __restrict__ scale_p, const float* __restrict__ zp_p,
    signed char* __restrict__ xi, signed char* __restrict__ qsT,
    float* __restrict__ am, float* __restrict__ bm) {
  __shared__ __align__(16) int qtile[64][68];
  __shared__ float red[8];
  const int t = threadIdx.x;

  if (blockIdx.x < 4096) {
    // ---- x path: one block per row ----
    const size_t row = blockIdx.x;
    const float* xr = x + row * (size_t)K_DIM;
    float4 v[4];
    float amax = 0.f;
#pragma unroll
    for (int i = 0; i < 4; ++i) {
      v[i] = *(const float4*)(xr + (i * 256 + t) * 4);
      amax = fmaxf(amax, fmaxf(fmaxf(fabsf(v[i].x), fabsf(v[i].y)),
                               fmaxf(fabsf(v[i].z), fabsf(v[i].w))));
    }
#pragma unroll
    for (int o = 32; o > 0; o >>= 1)
      amax = fmaxf(amax, __shfl_down(amax, o, 64));
    if ((t & 63) == 0) red[t >> 6] = amax;
    __syncthreads();
    amax = fmaxf(fmaxf(fmaxf(red[0], red[1]), fmaxf(red[2], red[3])), 1e-20f);
    const float inv = 127.f / amax;

    int ssum = 0;
    signed char* out = xi + row * (size_t)K_DIM;
#pragma unroll
    for (int i = 0; i < 4; ++i) {
      const int ia = __float2int_rn(v[i].x * inv);
      const int ib = __float2int_rn(v[i].y * inv);
      const int ic = __float2int_rn(v[i].z * inv);
      const int id = __float2int_rn(v[i].w * inv);
      ssum += ia + ib + ic + id;
      const int pk =
          (ia & 255) | ((ib & 255) << 8) | ((ic & 255) << 16) | (id << 24);
      *(int*)(out + (i * 256 + t) * 4) = pk;
    }
    float fs = (float)ssum;
#pragma unroll
    for (int o = 32; o > 0; o >>= 1) fs += __shfl_down(fs, o, 64);
    if ((t & 63) == 0) red[4 + (t >> 6)] = fs;
    __syncthreads();
    if (t == 0) {
      const float a = scale_p[0] * amax * (1.f / 127.f);
      am[row] = a;
      bm[row] = a * (128.f - zp_p[0]) * (red[4] + red[5] + red[6] + red[7]);
    }
  } else {
    // ---- w path: 64x64 transpose tile ----
    const int bid = blockIdx.x - 4096;
    const int k0 = (bid & 63) << 6;
    const int n0 = (bid >> 6) << 6;
    {
      const int c = t & 15;
      const int r0 = t >> 4;
#pragma unroll
      for (int i = 0; i < 4; ++i) {
        const int r = r0 + i * 16;
        const int4 v =
            *(const int4*)(q + (size_t)(k0 + r) * N_DIM + n0 + c * 4);
        *(int4*)&qtile[r][c * 4] = v;
      }
    }
    __syncthreads();
    {
      const int kc = t & 15;
      const int g = t >> 4;
      int4 v[4];
#pragma unroll
      for (int i = 0; i < 4; ++i)
        v[i] = *(const int4*)&qtile[kc * 4 + i][g * 4];
#pragma unroll
      for (int j = 0; j < 4; ++j) {
        const int b0 = ((&v[0].x)[j] - 128) & 255;
        const int b1 = ((&v[1].x)[j] - 128) & 255;
        const int b2 = ((&v[2].x)[j] - 128) & 255;
        const int b3 = ((&v[3].x)[j] - 128) & 255;
        const int pk = b0 | (b1 << 8) | (b2 << 16) | (b3 << 24);
        *(int*)(qsT + (size_t)(n0 + g * 4 + j) * K_DIM + k0 + kc * 4) = pk;
      }
    }
  }
}

// ---------------------------------------------------------------------------
// GEMM: acc[m][n] = sum_k xi[m][k]*qs[n][k] via mfma_i32_32x32x32_i8,
// y = am[m]*acc + bm[m] + bias[n].
// Same staging as R4 (128B LDS rows, 8x16B chunks, XOR swizzle
// stored = logical ^ (row&7), global_load_lds width=16).
// Fragment (32x32x32 i8): A[row=lane&31][k=(lane>>5)*16+j], j=0..15 -> one
// 16B chunk; 4 k-chunks per 128B row. Read chunk = (kc*2+khalf)^(row&7):
// per 16-lane b128 phase -> 8 bank-groups x 2 = conflict-free.
// C/D (shape-determined): col=lane&31, row=(reg&3)+8*(reg>>2)+4*(lane>>5).
// ---------------------------------------------------------------------------
__global__ __launch_bounds__(256) void gemm_kernel(
    const signed char* __restrict__ A,   // [M][K] i8
    const signed char* __restrict__ Bt,  // [N][K] i8
    const float* __restrict__ bias, const float* __restrict__ am,
    const float* __restrict__ bm, float* __restrict__ C) {
  __shared__ __align__(16) signed char As[BM * BKB];  // 16 KB
  __shared__ __align__(16) signed char Bs[BN * BKB];  // 16 KB

  const int tid = threadIdx.x;
  const int wave = tid >> 6;
  const int lane = tid & 63;
  const int wm = wave & 1;
  const int wn = wave >> 1;

  const int bmk = blockIdx.x & 31;
  const int bn = blockIdx.x >> 5;
  const size_t m0 = (size_t)bmk * BM;
  const size_t n0 = (size_t)bn * BN;

  const int srow = lane >> 3;
  const int schunk = (lane & 7) ^ (lane >> 3);

  const int r32 = lane & 31;   // row within a 32-tile
  const int khalf = lane >> 5; // k-half selector
  const int rxor = r32 & 7;

  i32x16 acc[2][2];
#pragma unroll
  for (int i = 0; i < 2; ++i)
#pragma unroll
    for (int j = 0; j < 2; ++j)
#pragma unroll
      for (int r = 0; r < 16; ++r) acc[i][j][r] = 0;

  const signed char* Abase = A + m0 * K_DIM;
  const signed char* Bbase = Bt + n0 * K_DIM;

  for (int k0 = 0; k0 < K_DIM; k0 += BKB) {
#pragma unroll
    for (int j = 0; j < 4; ++j) {
      const int rbase = wave * 32 + j * 8;
      const int row = rbase + srow;
      const size_t goff = (size_t)row * K_DIM + k0 + schunk * 16;
      async_copy16(Abase + goff, As + rbase * BKB);
      async_copy16(Bbase + goff, Bs + rbase * BKB);
    }
    __syncthreads();

#pragma unroll
    for (int kc = 0; kc < 4; ++kc) {
      const int ch = (kc * 2 + khalf) ^ rxor;
      i32x4 af[2], bfr[2];
#pragma unroll
      for (int t = 0; t < 2; ++t) {
        const int ar = wm * 64 + t * 32 + r32;
        const int br = wn * 64 + t * 32 + r32;
        af[t] = *(const i32x4*)(As + ar * BKB + ch * 16);
        bfr[t] = *(const i32x4*)(Bs + br * BKB + ch * 16);
      }
#pragma unroll
      for (int i = 0; i < 2; ++i)
#pragma unroll
        for (int j = 0; j < 2; ++j)
          acc[i][j] = __builtin_amdgcn_mfma_i32_32x32x32_i8(
              af[i], bfr[j], acc[i][j], 0, 0, 0);
    }
    __syncthreads();
  }

  // Epilogue: col = lane&31, row = (reg&3) + 8*(reg>>2) + 4*khalf.
#pragma unroll
  for (int i = 0; i < 2; ++i) {
    const size_t mb = m0 + wm * 64 + i * 32 + khalf * 4;
#pragma unroll
    for (int j = 0; j < 2; ++j) {
      const size_t n = n0 + wn * 64 + j * 32 + r32;
      const float bv = bias[n];
#pragma unroll
      for (int r = 0; r < 16; ++r) {
        const size_t m = mb + (r & 3) + 8 * (r >> 2);
        C[m * N_DIM + n] = fmaf(am[m], (float)acc[i][j][r], bm[m] + bv);
      }
    }
  }
}

// ---------------------------------------------------------------------------
extern "C" void kernel_launch(void* const* d_in, const int* in_sizes, int n_in,
                              void* d_out, int out_size, void* d_ws,
                              size_t ws_size, hipStream_t stream) {
  const float* x = (const float*)d_in[0];
  const int* q = (const int*)d_in[1];
  const float* scale = (const float*)d_in[2];
  const float* zp = (const float*)d_in[3];
  const float* bias = (const float*)d_in[4];
  float* out = (float*)d_out;

  char* ws = (char*)d_ws;
  signed char* xi = (signed char*)ws;                           // 16 MB
  signed char* qsT = (signed char*)(ws + ((size_t)16 << 20));   // 16 MB
  float* am = (float*)(ws + ((size_t)32 << 20));                // 16 KB
  float* bm = (float*)(ws + ((size_t)32 << 20) + (16 << 10));   // 16 KB

  prep_kernel<<<8192, 256, 0, stream>>>(x, q, scale, zp, xi, qsT, am, bm);
  gemm_kernel<<<1024, 256, 0, stream>>>(xi, qsT, bias, am, bm, out);
}